// Round 1
// baseline (167.006 us; speedup 1.0000x reference)
//
#include <hip/hip_runtime.h>

// Relation Graph Attention (RGAT), MI355X.
// R=3 relations, B=2, N=2048 nodes, CIN=256, NH=4 heads, D=64.
// Pipeline:
//  K0  : W[r][k][o] -> Wt bf16 [r][o][k]            (B-operand layout for K1)
//  K0b : xo[b][n][d] = xs @ W_out                   (residual term)
//  K1  : hs = xs @ W[r] (MFMA bf16); epilogue: ei/ej dots, V^T bf16 store
//  K2  : per (r,b,itile,jquarter): P = adj*exp(leakyrelu(ei+ej)) built in regs
//        as MFMA A-frags; num += P@V (MFMA), den += rowsum(P)
//  K3  : out = xo + sum_r (sum_js num)/(sum_js den)

constexpr int R_ = 3, B_ = 2, N_ = 2048, CIN_ = 256, NH_ = 4, D_ = 64, NHD_ = 256;
constexpr int JS_ = 4;                 // j-splits in K2
constexpr int JR_ = N_ / JS_;          // 512 j per block
constexpr float LEAKY = 0.1f;

typedef float f32x4 __attribute__((ext_vector_type(4)));
typedef __bf16 bf16x8 __attribute__((ext_vector_type(8)));

// workspace layout (bytes)
constexpr size_t OFF_WT  = 0;                                      // ushort [R][NHD][CIN]
constexpr size_t SZ_WT   = (size_t)R_ * NHD_ * CIN_ * 2;
constexpr size_t OFF_VT  = OFF_WT + SZ_WT;                         // ushort [R][B][NH][D][N]
constexpr size_t SZ_VT   = (size_t)R_ * B_ * NH_ * D_ * N_ * 2;
constexpr size_t OFF_EI  = OFF_VT + SZ_VT;                         // float [R][B][NH][N]
constexpr size_t SZ_E    = (size_t)R_ * B_ * NH_ * N_ * 4;
constexpr size_t OFF_EJ  = OFF_EI + SZ_E;
constexpr size_t OFF_XO  = OFF_EJ + SZ_E;                          // float [B][N][D]
constexpr size_t SZ_XO   = (size_t)B_ * N_ * D_ * 4;
constexpr size_t OFF_NUM = OFF_XO + SZ_XO;                         // float [JS][R][B][NH][N][D]
constexpr size_t SZ_NUM  = (size_t)JS_ * R_ * B_ * NH_ * N_ * D_ * 4;
constexpr size_t OFF_DEN = OFF_NUM + SZ_NUM;                       // float [JS][R][B][NH][N]

__device__ __forceinline__ unsigned short f2bf_bits(float f) {
    __bf16 b = (__bf16)f;
    return __builtin_bit_cast(unsigned short, b);
}

// ---------------- K0: transpose+cast W -> Wt bf16 [r][o][k] ----------------
__global__ void k0_wt(const float* __restrict__ W, unsigned short* __restrict__ Wt) {
    int of = blockIdx.x * 256 + threadIdx.x;       // 0..196607
    int r = of >> 16;
    int rem = of & 65535;
    int o = rem >> 8;
    int k = rem & 255;
    float v = W[((size_t)(r * CIN_ + k)) * NHD_ + o];
    Wt[of] = f2bf_bits(v);                         // Wt[r][o][k] flat == of
}

// ---------------- K0b: xo = xs @ W_out  (f32 vector) ----------------
__global__ __launch_bounds__(256) void k0_xo(const float* __restrict__ xs,
                                             const float* __restrict__ Wout,
                                             float* __restrict__ xo) {
    int flat_row = blockIdx.x * 4 + (threadIdx.x >> 6);   // 0..4095 = b*N+n
    int d = threadIdx.x & 63;
    const float* xrow = xs + (size_t)flat_row * CIN_;
    float acc = 0.f;
#pragma unroll 8
    for (int k = 0; k < CIN_; ++k)
        acc += xrow[k] * Wout[k * D_ + d];
    xo[(size_t)flat_row * D_ + d] = acc;
}

// ---------------- K1: hs GEMM + ei/ej + V^T store ----------------
// grid: R*B*(N/64) = 192 blocks, 256 threads (4 waves; wave w = rows w*16..w*16+15)
__global__ __launch_bounds__(256) void k1_hs(const float* __restrict__ xs,
                                             const unsigned short* __restrict__ Wt,
                                             const float* __restrict__ al,
                                             const float* __restrict__ ar,
                                             unsigned short* __restrict__ Vt,
                                             float* __restrict__ ei,
                                             float* __restrict__ ej) {
    __shared__ unsigned short lds[64][NHD_ + 8];

    int x = blockIdx.x;
    int itile = x & 31;
    int b = (x >> 5) & 1;
    int r = x >> 6;
    int tid = threadIdx.x;
    int l = tid & 63;
    int w = tid >> 6;
    int l15 = l & 15;
    int lg = l >> 4;
    int n0 = itile * 64;

    const float* xrow = xs + ((size_t)(b * N_ + n0 + w * 16 + l15)) * CIN_;
    const unsigned short* wt_base = Wt + (size_t)r * NHD_ * CIN_;

    f32x4 acc[16] = {};

#pragma unroll
    for (int ks = 0; ks < 8; ++ks) {
        int k8 = ks * 32 + lg * 8;
        float4 x0 = *(const float4*)(xrow + k8);
        float4 x1 = *(const float4*)(xrow + k8 + 4);
        bf16x8 a;
        a[0] = (__bf16)x0.x; a[1] = (__bf16)x0.y; a[2] = (__bf16)x0.z; a[3] = (__bf16)x0.w;
        a[4] = (__bf16)x1.x; a[5] = (__bf16)x1.y; a[6] = (__bf16)x1.z; a[7] = (__bf16)x1.w;
#pragma unroll
        for (int nf = 0; nf < 16; ++nf) {
            bf16x8 bf = *(const bf16x8*)(wt_base + ((size_t)(nf * 16 + l15)) * CIN_ + k8);
            acc[nf] = __builtin_amdgcn_mfma_f32_16x16x32_bf16(a, bf, acc[nf], 0, 0, 0);
        }
    }

    // --- ei/ej epilogue: rows i = n0 + w*16 + lg*4 + reg, col = nf*16+l15 ---
    float alv[4], arv[4];
#pragma unroll
    for (int q = 0; q < 4; ++q) {
        alv[q] = al[r * D_ + q * 16 + l15];
        arv[q] = ar[r * D_ + q * 16 + l15];
    }
#pragma unroll
    for (int h = 0; h < NH_; ++h) {
#pragma unroll
        for (int reg = 0; reg < 4; ++reg) {
            float pi = 0.f, pj = 0.f;
#pragma unroll
            for (int q = 0; q < 4; ++q) {
                float v = acc[4 * h + q][reg];
                pi += v * alv[q];
                pj += v * arv[q];
            }
#pragma unroll
            for (int m = 1; m < 16; m <<= 1) {
                pi += __shfl_xor(pi, m, 64);
                pj += __shfl_xor(pj, m, 64);
            }
            if (l15 == 0) {
                int i = n0 + w * 16 + lg * 4 + reg;
                size_t eoff = ((size_t)((r * B_ + b) * NH_ + h)) * N_ + i;
                ei[eoff] = pi;
                ej[eoff] = pj;
            }
        }
    }

    // --- V^T store via LDS transpose ---
#pragma unroll
    for (int nf = 0; nf < 16; ++nf)
#pragma unroll
        for (int reg = 0; reg < 4; ++reg) {
            int row = w * 16 + lg * 4 + reg;       // local n
            int col = nf * 16 + l15;               // h*64+d
            lds[row][col] = f2bf_bits(acc[nf][reg]);
        }
    __syncthreads();

#pragma unroll
    for (int it = 0; it < 16; ++it) {
        int idx = it * 256 + tid;                  // 0..4095; each covers 4 n
        int c = idx >> 4;                          // 0..255 column
        int nn = (idx & 15) * 4;
        ushort4 v;
        v.x = lds[nn + 0][c];
        v.y = lds[nn + 1][c];
        v.z = lds[nn + 2][c];
        v.w = lds[nn + 3][c];
        int hh = c >> 6, dd = c & 63;
        size_t voff = (((size_t)((r * B_ + b) * NH_ + hh)) * D_ + dd) * N_ + n0 + nn;
        *(ushort4*)(Vt + voff) = v;
    }
}

// ---------------- K2: masked-exp attention, P@V ----------------
// grid: JS*R*B*(N/64) = 768 blocks of 512 threads (8 waves = 4 heads x 2 m-halves)
__global__ __launch_bounds__(512) void k2_attn(const float* __restrict__ adjs,
                                               const unsigned short* __restrict__ Vt,
                                               const float* __restrict__ ei,
                                               const float* __restrict__ ej,
                                               float* __restrict__ num_part,
                                               float* __restrict__ den_part) {
    int x = blockIdx.x;
    int js = x & 3;
    int itile = (x >> 2) & 31;
    int b = (x >> 7) & 1;
    int r = x >> 8;
    int tid = threadIdx.x;
    int l = tid & 63;
    int w = tid >> 6;
    int h = w >> 1;
    int mh = w & 1;
    int l15 = l & 15;
    int lg = l >> 4;
    int i_base = itile * 64 + mh * 32;
    int j0 = js * JR_;

    const float* adj_base = adjs + ((size_t)(r * B_ + b)) * N_ * N_;
    const float* ej_base = ej + ((size_t)((r * B_ + b) * NH_ + h)) * N_;
    const float* ei_base = ei + ((size_t)((r * B_ + b) * NH_ + h)) * N_;
    const unsigned short* vt_base = Vt + ((size_t)((r * B_ + b) * NH_ + h)) * D_ * N_;

    float eiv0 = ei_base[i_base + l15];        // A-frag row for mf=0
    float eiv1 = ei_base[i_base + 16 + l15];   // A-frag row for mf=1

    f32x4 acc[2][4] = {};
    float dpart0 = 0.f, dpart1 = 0.f;

    for (int kk = 0; kk < JR_ / 32; ++kk) {    // 16 k-steps of 32 j
        int j = j0 + kk * 32 + lg * 8;
        float4 e0 = *(const float4*)(ej_base + j);
        float4 e1 = *(const float4*)(ej_base + j + 4);
        float ejv[8] = {e0.x, e0.y, e0.z, e0.w, e1.x, e1.y, e1.z, e1.w};

        bf16x8 afrag[2];
#pragma unroll
        for (int mf = 0; mf < 2; ++mf) {
            float eiv = mf ? eiv1 : eiv0;
            const float* arow = adj_base + ((size_t)(i_base + mf * 16 + l15)) * N_ + j;
            float4 a0 = *(const float4*)(arow);
            float4 a1 = *(const float4*)(arow + 4);
            float av[8] = {a0.x, a0.y, a0.z, a0.w, a1.x, a1.y, a1.z, a1.w};
            float ds = 0.f;
#pragma unroll
            for (int e = 0; e < 8; ++e) {
                float t = eiv + ejv[e];
                float lr = fmaxf(t, LEAKY * t);     // leaky relu
                float p = av[e] * __expf(lr);       // adj in {0,1}: mask via mul
                ds += p;
                afrag[mf][e] = (__bf16)p;
            }
            if (mf) dpart1 += ds; else dpart0 += ds;
        }
#pragma unroll
        for (int nf = 0; nf < 4; ++nf) {
            bf16x8 bfrag = *(const bf16x8*)(vt_base + ((size_t)(nf * 16 + l15)) * N_ + j);
            acc[0][nf] = __builtin_amdgcn_mfma_f32_16x16x32_bf16(afrag[0], bfrag, acc[0][nf], 0, 0, 0);
            acc[1][nf] = __builtin_amdgcn_mfma_f32_16x16x32_bf16(afrag[1], bfrag, acc[1][nf], 0, 0, 0);
        }
    }

    // --- denominators: reduce over the 4 lane-groups holding the same row ---
    size_t dbase = ((size_t)(((js * R_ + r) * B_ + b) * NH_ + h)) * N_;
#pragma unroll
    for (int mf = 0; mf < 2; ++mf) {
        float d0 = mf ? dpart1 : dpart0;
        d0 += __shfl_xor(d0, 16, 64);
        d0 += __shfl_xor(d0, 32, 64);
        if (l < 16)
            den_part[dbase + i_base + mf * 16 + l] = d0;
    }

    // --- numerators (unnormalized) ---
    float* np_base = num_part + ((size_t)(((js * R_ + r) * B_ + b) * NH_ + h)) * N_ * D_;
#pragma unroll
    for (int mf = 0; mf < 2; ++mf)
#pragma unroll
        for (int nf = 0; nf < 4; ++nf)
#pragma unroll
            for (int reg = 0; reg < 4; ++reg) {
                int i = i_base + mf * 16 + lg * 4 + reg;
                int d = nf * 16 + l15;
                np_base[(size_t)i * D_ + d] = acc[mf][nf][reg];
            }
}

// ---------------- K3: combine ----------------
__global__ void k3_out(const float* __restrict__ num_part,
                       const float* __restrict__ den_part,
                       const float* __restrict__ xo,
                       float* __restrict__ out) {
    size_t o = (size_t)blockIdx.x * 256 + threadIdx.x;   // < 1048576
    int b = (int)(o >> 19);
    int n = (int)(o >> 8) & 2047;
    int c = (int)(o & 255);
    int h = c >> 6, d = c & 63;

    float acc = xo[((size_t)(b * N_ + n)) * D_ + d];
#pragma unroll
    for (int r = 0; r < R_; ++r) {
        size_t nidx = (((size_t)((r * B_ + b) * NH_ + h)) * N_ + n) * D_ + d;
        size_t didx = ((size_t)((r * B_ + b) * NH_ + h)) * N_ + n;
        float num = 0.f, den = 0.f;
#pragma unroll
        for (int js = 0; js < JS_; ++js) {
            num += num_part[(size_t)js * R_ * B_ * NH_ * N_ * D_ + nidx];
            den += den_part[(size_t)js * R_ * B_ * NH_ * N_ + didx];
        }
        if (den > 0.f) acc += num / den;
    }
    out[o] = acc;
}

extern "C" void kernel_launch(void* const* d_in, const int* in_sizes, int n_in,
                              void* d_out, int out_size, void* d_ws, size_t ws_size,
                              hipStream_t stream) {
    const float* xs   = (const float*)d_in[0];
    const float* adjs = (const float*)d_in[1];
    const float* W    = (const float*)d_in[2];
    const float* al   = (const float*)d_in[3];
    const float* ar   = (const float*)d_in[4];
    const float* Wout = (const float*)d_in[5];
    float* out = (float*)d_out;

    char* ws = (char*)d_ws;
    unsigned short* Wt = (unsigned short*)(ws + OFF_WT);
    unsigned short* Vt = (unsigned short*)(ws + OFF_VT);
    float* ei  = (float*)(ws + OFF_EI);
    float* ej  = (float*)(ws + OFF_EJ);
    float* xo  = (float*)(ws + OFF_XO);
    float* num = (float*)(ws + OFF_NUM);
    float* den = (float*)(ws + OFF_DEN);

    k0_wt<<<dim3((R_ * NHD_ * CIN_) / 256), dim3(256), 0, stream>>>(W, Wt);
    k0_xo<<<dim3(B_ * N_ / 4), dim3(256), 0, stream>>>(xs, Wout, xo);
    k1_hs<<<dim3(R_ * B_ * (N_ / 64)), dim3(256), 0, stream>>>(xs, Wt, al, ar, Vt, ei, ej);
    k2_attn<<<dim3(JS_ * R_ * B_ * (N_ / 64)), dim3(512), 0, stream>>>(adjs, Vt, ei, ej, num, den);
    k3_out<<<dim3((B_ * N_ * NHD_) / 256), dim3(256), 0, stream>>>(num, den, xo, out);
}

// Round 2
// 115.404 us; speedup vs baseline: 1.4472x; 1.4472x over previous
//
#include <hip/hip_runtime.h>

// Relation Graph Attention (RGAT), MI355X. v2.
// R=3, B=2, N=2048, CIN=256, NH=4, D=64.
//  K0  : W -> Wt bf16 [r][o][k]
//  K0b : xo = xs @ W_out
//  K1  : hs = xs @ W[r] (MFMA); epilogue: ei/ej (prescaled by log2e) + V in
//        vt2 MFMA-B-fragment-tiled layout [(jt,nf)][lane][8] (coalesced K2 loads)
//  K2  : per (r,b,itile32,jhalf): LDS-staged adj (dbuf, issue-early/write-late),
//        P = adj*exp2(lrelu(ei'+ej')) in regs, P@V MFMA, den rowsum
//  K3  : out = xo + sum_r (sum_js num)/(sum_js den)

constexpr int R_ = 3, B_ = 2, N_ = 2048, CIN_ = 256, NH_ = 4, D_ = 64, NHD_ = 256;
constexpr int JS_ = 2;                 // j-splits in K2
constexpr int JR_ = N_ / JS_;          // 1024 j per block
constexpr int ITILE_ = 32;             // i rows per K2 block
constexpr int BK_ = 64;                // j per LDS stage
constexpr int NST_ = JR_ / BK_;        // 16 stages
constexpr float LEAKY = 0.1f;
constexpr float LOG2E = 1.4426950408889634f;

typedef float f32x4 __attribute__((ext_vector_type(4)));
typedef __bf16 bf16x8 __attribute__((ext_vector_type(8)));

// workspace layout (bytes)
constexpr size_t OFF_WT  = 0;                                      // ushort [R][NHD][CIN]
constexpr size_t SZ_WT   = (size_t)R_ * NHD_ * CIN_ * 2;
constexpr size_t OFF_VT  = OFF_WT + SZ_WT;                         // ushort [R][B][NH][ D*N in frag-tile order ]
constexpr size_t SZ_VT   = (size_t)R_ * B_ * NH_ * D_ * N_ * 2;
constexpr size_t OFF_EI  = OFF_VT + SZ_VT;                         // float [R][B][NH][N]  (prescaled by log2e)
constexpr size_t SZ_E    = (size_t)R_ * B_ * NH_ * N_ * 4;
constexpr size_t OFF_EJ  = OFF_EI + SZ_E;
constexpr size_t OFF_XO  = OFF_EJ + SZ_E;                          // float [B][N][D]
constexpr size_t SZ_XO   = (size_t)B_ * N_ * D_ * 4;
constexpr size_t OFF_NUM = OFF_XO + SZ_XO;                         // float [JS][R][B][NH][N][D]
constexpr size_t SZ_NUM  = (size_t)JS_ * R_ * B_ * NH_ * N_ * D_ * 4;
constexpr size_t OFF_DEN = OFF_NUM + SZ_NUM;                       // float [JS][R][B][NH][N]

__device__ __forceinline__ unsigned short f2bf_bits(float f) {
    __bf16 b = (__bf16)f;
    return __builtin_bit_cast(unsigned short, b);
}

// ---------------- K0: transpose+cast W -> Wt bf16 [r][o][k] ----------------
__global__ void k0_wt(const float* __restrict__ W, unsigned short* __restrict__ Wt) {
    int of = blockIdx.x * 256 + threadIdx.x;       // 0..196607
    int r = of >> 16;
    int rem = of & 65535;
    int o = rem >> 8;
    int k = rem & 255;
    float v = W[((size_t)(r * CIN_ + k)) * NHD_ + o];
    Wt[of] = f2bf_bits(v);                         // Wt[r][o][k] flat == of
}

// ---------------- K0b: xo = xs @ W_out  (f32 vector) ----------------
__global__ __launch_bounds__(256) void k0_xo(const float* __restrict__ xs,
                                             const float* __restrict__ Wout,
                                             float* __restrict__ xo) {
    int flat_row = blockIdx.x * 4 + (threadIdx.x >> 6);   // 0..4095 = b*N+n
    int d = threadIdx.x & 63;
    const float* xrow = xs + (size_t)flat_row * CIN_;
    float acc = 0.f;
#pragma unroll 8
    for (int k = 0; k < CIN_; ++k)
        acc += xrow[k] * Wout[k * D_ + d];
    xo[(size_t)flat_row * D_ + d] = acc;
}

// ---------------- K1: hs GEMM + ei/ej + vt2 fragment-tiled store ----------------
// grid: R*B*(N/64) = 192 blocks, 256 threads (4 waves; wave w = rows w*16..w*16+15)
__global__ __launch_bounds__(256) void k1_hs(const float* __restrict__ xs,
                                             const unsigned short* __restrict__ Wt,
                                             const float* __restrict__ al,
                                             const float* __restrict__ ar,
                                             unsigned short* __restrict__ Vt,
                                             float* __restrict__ ei,
                                             float* __restrict__ ej) {
    __shared__ unsigned short lds[64][NHD_ + 8];

    int x = blockIdx.x;
    int itile = x & 31;
    int b = (x >> 5) & 1;
    int r = x >> 6;
    int tid = threadIdx.x;
    int l = tid & 63;
    int w = tid >> 6;
    int l15 = l & 15;
    int lg = l >> 4;
    int n0 = itile * 64;

    const float* xrow = xs + ((size_t)(b * N_ + n0 + w * 16 + l15)) * CIN_;
    const unsigned short* wt_base = Wt + (size_t)r * NHD_ * CIN_;

    f32x4 acc[16] = {};

#pragma unroll
    for (int ks = 0; ks < 8; ++ks) {
        int k8 = ks * 32 + lg * 8;
        float4 x0 = *(const float4*)(xrow + k8);
        float4 x1 = *(const float4*)(xrow + k8 + 4);
        bf16x8 a;
        a[0] = (__bf16)x0.x; a[1] = (__bf16)x0.y; a[2] = (__bf16)x0.z; a[3] = (__bf16)x0.w;
        a[4] = (__bf16)x1.x; a[5] = (__bf16)x1.y; a[6] = (__bf16)x1.z; a[7] = (__bf16)x1.w;
#pragma unroll
        for (int nf = 0; nf < 16; ++nf) {
            bf16x8 bf = *(const bf16x8*)(wt_base + ((size_t)(nf * 16 + l15)) * CIN_ + k8);
            acc[nf] = __builtin_amdgcn_mfma_f32_16x16x32_bf16(a, bf, acc[nf], 0, 0, 0);
        }
    }

    // --- ei/ej epilogue (prescaled by log2e): rows i = n0+w*16+lg*4+reg ---
    float alv[4], arv[4];
#pragma unroll
    for (int q = 0; q < 4; ++q) {
        alv[q] = al[r * D_ + q * 16 + l15];
        arv[q] = ar[r * D_ + q * 16 + l15];
    }
#pragma unroll
    for (int h = 0; h < NH_; ++h) {
#pragma unroll
        for (int reg = 0; reg < 4; ++reg) {
            float pi = 0.f, pj = 0.f;
#pragma unroll
            for (int q = 0; q < 4; ++q) {
                float v = acc[4 * h + q][reg];
                pi += v * alv[q];
                pj += v * arv[q];
            }
#pragma unroll
            for (int m = 1; m < 16; m <<= 1) {
                pi += __shfl_xor(pi, m, 64);
                pj += __shfl_xor(pj, m, 64);
            }
            if (l15 == 0) {
                int i = n0 + w * 16 + lg * 4 + reg;
                size_t eoff = ((size_t)((r * B_ + b) * NH_ + h)) * N_ + i;
                ei[eoff] = pi * LOG2E;
                ej[eoff] = pj * LOG2E;
            }
        }
    }

    // --- V store in MFMA-B-fragment tile order via LDS transpose ---
    // vt2[(r,b,h)][(jt*4+nf)*64 + lane][e 0..7] = hs[n = jt*32+(lane>>4)*8+e][h][d = nf*16+(lane&15)]
#pragma unroll
    for (int nf = 0; nf < 16; ++nf)
#pragma unroll
        for (int reg = 0; reg < 4; ++reg) {
            int row = w * 16 + lg * 4 + reg;       // local n
            int col = nf * 16 + l15;               // h*64+d
            lds[row][col] = f2bf_bits(acc[nf][reg]);
        }
    __syncthreads();

#pragma unroll
    for (int it = 0; it < 16; ++it) {
        int flat = it * 256 + tid;                 // 0..4095
        int e4  = flat & 1;                        // which ushort4 half
        int ll  = (flat >> 1) & 63;                // dest lane
        int nf  = (flat >> 7) & 3;
        int hh  = (flat >> 9) & 3;
        int jtl = (flat >> 11) & 1;                // local j-tile (32 n each)
        int c = hh * 64 + nf * 16 + (ll & 15);
        int nb = jtl * 32 + ((ll >> 4) * 8) + e4 * 4;
        ushort4 v;
        v.x = lds[nb + 0][c];
        v.y = lds[nb + 1][c];
        v.z = lds[nb + 2][c];
        v.w = lds[nb + 3][c];
        size_t dst = ((size_t)((r * B_ + b) * NH_ + hh)) * (size_t)(D_ * N_)
                   + ((size_t)((itile * 2 + jtl) * 4 + nf) * 64 + ll) * 8 + e4 * 4;
        *(ushort4*)(Vt + dst) = v;
    }
}

// ---------------- K2: masked-exp attention, P@V ----------------
// grid: R*B*(N/32)*JS = 768 blocks of 512 threads (8 waves = 4 heads x 2 row-halves)
__global__ __launch_bounds__(512) void k2_attn(const float* __restrict__ adjs,
                                               const unsigned short* __restrict__ vt2,
                                               const float* __restrict__ ei,
                                               const float* __restrict__ ej,
                                               float* __restrict__ num_part,
                                               float* __restrict__ den_part) {
    __shared__ __align__(16) float adj_lds[2][ITILE_][BK_ + 4];

    int x = blockIdx.x;
    int js = x & 1;
    int itile = (x >> 1) & 63;
    int b = (x >> 7) & 1;
    int r = x >> 8;
    int tid = threadIdx.x;
    int l = tid & 63;
    int w = tid >> 6;
    int h = w & 3;
    int mh = w >> 2;
    int l15 = l & 15;
    int lg = l >> 4;
    int i0 = itile * ITILE_;
    int iw = i0 + mh * 16;                 // wave's first i row
    int j0 = js * JR_;

    const float* adj_base = adjs + ((size_t)(r * B_ + b)) * N_ * N_;
    const float* ejb = ej + ((size_t)((r * B_ + b) * NH_ + h)) * N_;
    const float* eib = ei + ((size_t)((r * B_ + b) * NH_ + h)) * N_;
    const unsigned short* vtb = vt2 + ((size_t)((r * B_ + b) * NH_ + h)) * (size_t)(D_ * N_);

    float eiv = eib[iw + l15];             // A-frag row logit

    // staging: thread -> (row, 16B granule)
    int srow = tid >> 4, scol = tid & 15;
    const float* src = adj_base + ((size_t)(i0 + srow)) * N_ + j0 + scol * 4;

    f32x4 acc[4] = {};
    float dsum = 0.f;

    float4 stg = *(const float4*)(src);    // stage 0
    *(float4*)&adj_lds[0][srow][scol * 4] = stg;
    __syncthreads();

    for (int st = 0; st < NST_; ++st) {
        int cur = st & 1;
        bool more = (st + 1 < NST_);
        if (more) stg = *(const float4*)(src + (st + 1) * BK_);   // issue early (T14)

#pragma unroll
        for (int sub = 0; sub < 2; ++sub) {
            int jsb = j0 + st * BK_ + sub * 32;     // sub-tile j base (global)
            int jt = jsb >> 5;                       // global 32-j tile index
            float4 e0 = *(const float4*)(ejb + jsb + lg * 8);
            float4 e1 = *(const float4*)(ejb + jsb + lg * 8 + 4);
            const float* ap = &adj_lds[cur][mh * 16 + l15][sub * 32 + lg * 8];
            float4 a0 = *(const float4*)(ap);
            float4 a1 = *(const float4*)(ap + 4);
            float ev[8] = {e0.x, e0.y, e0.z, e0.w, e1.x, e1.y, e1.z, e1.w};
            float av[8] = {a0.x, a0.y, a0.z, a0.w, a1.x, a1.y, a1.z, a1.w};
            bf16x8 af;
#pragma unroll
            for (int e = 0; e < 8; ++e) {
                float t = eiv + ev[e];
                float lr = fmaxf(t, LEAKY * t);               // lrelu (log2-scaled)
                float p = av[e] * __builtin_amdgcn_exp2f(lr); // adj in {0,1}: mask via mul
                dsum += p;
                af[e] = (__bf16)p;
            }
#pragma unroll
            for (int nf = 0; nf < 4; ++nf) {
                bf16x8 bf = *(const bf16x8*)(vtb + ((size_t)(jt * 4 + nf) * 64 + l) * 8);
                acc[nf] = __builtin_amdgcn_mfma_f32_16x16x32_bf16(af, bf, acc[nf], 0, 0, 0);
            }
        }

        if (more) {
            *(float4*)&adj_lds[cur ^ 1][srow][scol * 4] = stg;  // write late
            __syncthreads();
        }
    }

    // --- denominator: reduce over the 4 lane-groups holding the same row ---
    float d0 = dsum;
    d0 += __shfl_xor(d0, 16, 64);
    d0 += __shfl_xor(d0, 32, 64);
    size_t dbase = ((size_t)(((js * R_ + r) * B_ + b) * NH_ + h)) * N_;
    if (l < 16)
        den_part[dbase + iw + l] = d0;

    // --- numerators (unnormalized partials) ---
    float* npb = num_part + ((size_t)(((js * R_ + r) * B_ + b) * NH_ + h)) * N_ * D_;
#pragma unroll
    for (int nf = 0; nf < 4; ++nf)
#pragma unroll
        for (int reg = 0; reg < 4; ++reg) {
            int i = iw + lg * 4 + reg;
            int d = nf * 16 + l15;
            npb[(size_t)i * D_ + d] = acc[nf][reg];
        }
}

// ---------------- K3: combine ----------------
__global__ void k3_out(const float* __restrict__ num_part,
                       const float* __restrict__ den_part,
                       const float* __restrict__ xo,
                       float* __restrict__ out) {
    size_t o = (size_t)blockIdx.x * 256 + threadIdx.x;   // < 1048576
    int b = (int)(o >> 19);
    int n = (int)(o >> 8) & 2047;
    int c = (int)(o & 255);
    int h = c >> 6, d = c & 63;

    float acc = xo[((size_t)(b * N_ + n)) * D_ + d];
#pragma unroll
    for (int r = 0; r < R_; ++r) {
        size_t nidx = (((size_t)((r * B_ + b) * NH_ + h)) * N_ + n) * D_ + d;
        size_t didx = ((size_t)((r * B_ + b) * NH_ + h)) * N_ + n;
        float num = 0.f, den = 0.f;
#pragma unroll
        for (int js = 0; js < JS_; ++js) {
            num += num_part[(size_t)js * R_ * B_ * NH_ * N_ * D_ + nidx];
            den += den_part[(size_t)js * R_ * B_ * NH_ * N_ + didx];
        }
        if (den > 0.f) acc += num / den;
    }
    out[o] = acc;
}

extern "C" void kernel_launch(void* const* d_in, const int* in_sizes, int n_in,
                              void* d_out, int out_size, void* d_ws, size_t ws_size,
                              hipStream_t stream) {
    const float* xs   = (const float*)d_in[0];
    const float* adjs = (const float*)d_in[1];
    const float* W    = (const float*)d_in[2];
    const float* al   = (const float*)d_in[3];
    const float* ar   = (const float*)d_in[4];
    const float* Wout = (const float*)d_in[5];
    float* out = (float*)d_out;

    char* ws = (char*)d_ws;
    unsigned short* Wt = (unsigned short*)(ws + OFF_WT);
    unsigned short* Vt = (unsigned short*)(ws + OFF_VT);
    float* ei  = (float*)(ws + OFF_EI);
    float* ej  = (float*)(ws + OFF_EJ);
    float* xo  = (float*)(ws + OFF_XO);
    float* num = (float*)(ws + OFF_NUM);
    float* den = (float*)(ws + OFF_DEN);

    k0_wt<<<dim3((R_ * NHD_ * CIN_) / 256), dim3(256), 0, stream>>>(W, Wt);
    k0_xo<<<dim3(B_ * N_ / 4), dim3(256), 0, stream>>>(xs, Wout, xo);
    k1_hs<<<dim3(R_ * B_ * (N_ / 64)), dim3(256), 0, stream>>>(xs, Wt, al, ar, Vt, ei, ej);
    k2_attn<<<dim3(R_ * B_ * (N_ / ITILE_) * JS_), dim3(512), 0, stream>>>(adjs, Vt, ei, ej, num, den);
    k3_out<<<dim3((B_ * N_ * NHD_) / 256), dim3(256), 0, stream>>>(num, den, xo, out);
}